// Round 1
// baseline (1865.109 us; speedup 1.0000x reference)
//
#include <hip/hip_runtime.h>
#include <math.h>

#define N_ANCH 120000
#define N_CLS  80
#define TOPK   4096
#define MAXDET 100
#define CONF   0.25f
#define IOUT   0.4f

// ---------- helpers ----------
__device__ __forceinline__ unsigned f2ord(float f) {
    unsigned u = __float_as_uint(f);
    return (u & 0x80000000u) ? ~u : (u | 0x80000000u);
}
__device__ __forceinline__ float ord2f(unsigned o) {
    unsigned u = (o & 0x80000000u) ? (o & 0x7FFFFFFFu) : ~o;
    return __uint_as_float(u);
}

// ---------- 0: zero hist + meta ----------
__global__ __launch_bounds__(1024) void k_zero(unsigned* hist, unsigned* meta) {
    int i = blockIdx.x * 1024 + threadIdx.x;
    if (i < 65536) hist[i] = 0u;
    if (i < 64) meta[i] = 0u;
}

// ---------- 1: decode anchors + histogram round 1 (bits 31:16 of ordered score) ----------
__global__ __launch_bounds__(256) void k_decode(const float* __restrict__ pred,
                                                unsigned* __restrict__ ord,
                                                int* __restrict__ lab,
                                                float4* __restrict__ box,
                                                unsigned* __restrict__ hist) {
    int a = blockIdx.x * 256 + threadIdx.x;
    if (a >= N_ANCH) return;
    const float* p = pred + (long)a * 85;
    float x = p[0], y = p[1], w = p[2], h = p[3], obj = p[4];
    float best = p[5];
    int bl = 0;
    for (int c = 1; c < N_CLS; ++c) {
        float v = p[5 + c];
        if (v > best) { best = v; bl = c; }   // first-max (argmax) semantics
    }
    float sc = obj * best;
    float hw = w * 0.5f, hh = h * 0.5f;
    float4 b;
    b.x = x - hw; b.y = y - hh; b.z = x + hw; b.w = y + hh;
    bool valid = sc > CONF;
    float m = valid ? sc : -INFINITY;
    unsigned o = f2ord(m);
    ord[a] = o;
    lab[a] = bl;
    box[a] = b;
    atomicAdd(&hist[o >> 16], 1u);
}

// ---------- 2/4: histogram select (suffix scan over 65536 bins) ----------
// mode 0: digit = ord>>16, target = TOPK; writes meta[0..2]; re-zeros hist.
// mode 1: digit = ord&0xFFFF (within bin meta[0]), target = meta[2]; writes meta[3..5].
__global__ __launch_bounds__(1024) void k_select(unsigned* hist, unsigned* meta, int mode) {
    __shared__ unsigned part[1024];
    int t = threadIdx.x;
    unsigned target = (mode == 0) ? (unsigned)TOPK : meta[2];
    int base = t * 64;
    unsigned local = 0;
    for (int i = 0; i < 64; ++i) local += hist[base + i];
    part[t] = local;
    __syncthreads();
    // inclusive suffix scan (Hillis-Steele)
    for (int off = 1; off < 1024; off <<= 1) {
        unsigned v = (t + off < 1024) ? part[t + off] : 0u;
        __syncthreads();
        part[t] += v;
        __syncthreads();
    }
    unsigned incl = part[t];
    unsigned after = (t + 1 < 1024) ? part[t + 1] : 0u;
    if (after < target && incl >= target) {   // unique boundary chunk
        unsigned run = after;
        for (int i = 63; i >= 0; --i) {
            unsigned c = hist[base + i];
            if (run + c >= target) {
                if (mode == 0) {
                    meta[0] = (unsigned)(base + i);  // b1
                    meta[1] = run;                   // count(digit > b1)
                    meta[2] = (unsigned)TOPK - run;  // rem for round 2
                } else {
                    meta[3] = (meta[0] << 16) | (unsigned)(base + i);  // T (32-bit threshold)
                    meta[4] = meta[1] + run;                           // count(ord > T)
                    meta[5] = meta[2] - run;                           // take this many from ord==T
                }
                break;
            }
            run += c;
        }
    }
    if (mode == 0) {
        for (int i = 0; i < 64; ++i) hist[base + i] = 0u;  // own chunk only: no hazard
    }
}

// ---------- 3: histogram round 2 (low 16 bits, only elements in bin b1) ----------
__global__ __launch_bounds__(256) void k_hist2(const unsigned* __restrict__ ord,
                                               const unsigned* __restrict__ meta,
                                               unsigned* __restrict__ hist) {
    int a = blockIdx.x * 256 + threadIdx.x;
    if (a >= N_ANCH) return;
    unsigned o = ord[a];
    if ((o >> 16) == meta[0]) atomicAdd(&hist[o & 0xFFFFu], 1u);
}

// ---------- 5: compact: keys for ord>T, index list for ord==T ----------
__global__ __launch_bounds__(256) void k_compact(const unsigned* __restrict__ ord,
                                                 unsigned* meta,
                                                 unsigned long long* __restrict__ keys,
                                                 unsigned* __restrict__ eq) {
    int a = blockIdx.x * 256 + threadIdx.x;
    if (a >= N_ANCH) return;
    unsigned o = ord[a];
    unsigned T = meta[3];
    if (o > T) {
        unsigned p = atomicAdd(&meta[6], 1u);
        keys[p] = ((unsigned long long)o << 32) | (unsigned)(~(unsigned)a);
    } else if (o == T) {
        unsigned p = atomicAdd(&meta[7], 1u);
        if (p < TOPK) eq[p] = (unsigned)a;
    }
}

// ---------- 6: sort tie indices ascending, append remEq smallest ----------
__global__ __launch_bounds__(1024) void k_eqsort(const unsigned* __restrict__ eq,
                                                 unsigned* meta,
                                                 unsigned long long* keys) {
    __shared__ unsigned s[TOPK];
    int t = threadIdx.x;
    unsigned n = meta[7]; if (n > TOPK) n = TOPK;
    unsigned remEq = meta[5];
    unsigned baseA = meta[4];
    unsigned T = meta[3];
    for (int i = t; i < TOPK; i += 1024) s[i] = (i < (int)n) ? eq[i] : 0xFFFFFFFFu;
    __syncthreads();
    for (int k = 2; k <= TOPK; k <<= 1)
        for (int j = k >> 1; j > 0; j >>= 1) {
            for (int idx = t; idx < TOPK; idx += 1024) {
                int ixj = idx ^ j;
                if (ixj > idx) {
                    unsigned a = s[idx], b = s[ixj];
                    bool asc = ((idx & k) == 0);
                    bool sw = asc ? (a > b) : (a < b);
                    if (sw) { s[idx] = b; s[ixj] = a; }
                }
            }
            __syncthreads();
        }
    for (unsigned r = t; r < remEq; r += 1024)
        keys[baseA + r] = ((unsigned long long)T << 32) | (unsigned)(~s[r]);
}

// ---------- 7: bitonic sort 4096 keys descending ----------
__global__ __launch_bounds__(1024) void k_sort(unsigned long long* keys) {
    __shared__ unsigned long long s[TOPK];  // 32 KB
    int t = threadIdx.x;
    for (int i = t; i < TOPK; i += 1024) s[i] = keys[i];
    __syncthreads();
    for (int k = 2; k <= TOPK; k <<= 1)
        for (int j = k >> 1; j > 0; j >>= 1) {
            for (int idx = t; idx < TOPK; idx += 1024) {
                int ixj = idx ^ j;
                if (ixj > idx) {
                    unsigned long long a = s[idx], b = s[ixj];
                    bool desc = ((idx & k) == 0);
                    bool sw = desc ? (a < b) : (a > b);
                    if (sw) { s[idx] = b; s[ixj] = a; }
                }
            }
            __syncthreads();
        }
    for (int i = t; i < TOPK; i += 1024) keys[i] = s[i];
}

// ---------- 8: gather candidate arrays + max_coord (atomicMax on positive-float bits) ----------
__global__ __launch_bounds__(256) void k_gather(const unsigned long long* __restrict__ keys,
                                                const int* __restrict__ lab,
                                                const float4* __restrict__ box,
                                                int* __restrict__ cIdx,
                                                float* __restrict__ cScore,
                                                int* __restrict__ cLab,
                                                float4* __restrict__ cBox,
                                                unsigned* meta) {
    int k = blockIdx.x * 256 + threadIdx.x;  // grid = 16 -> 4096
    unsigned long long key = keys[k];
    unsigned o = (unsigned)(key >> 32);
    unsigned a = ~(unsigned)(key & 0xFFFFFFFFu);
    float sc = ord2f(o);
    cIdx[k] = (int)a;
    cScore[k] = sc;
    cLab[k] = lab[a];
    float4 b = box[a];
    cBox[k] = b;
    if (sc > CONF) {  // max over where(valid, boxes, 0); result >= 0 so positive-bits atomicMax works
        if (b.x > 0.f) atomicMax(&meta[8], __float_as_uint(b.x));
        if (b.y > 0.f) atomicMax(&meta[8], __float_as_uint(b.y));
        if (b.z > 0.f) atomicMax(&meta[8], __float_as_uint(b.z));
        if (b.w > 0.f) atomicMax(&meta[8], __float_as_uint(b.w));
    }
}

// ---------- 9: offset boxes (class-separated) + areas, exact reference op order ----------
__global__ __launch_bounds__(256) void k_offbox(const int* __restrict__ cLab,
                                                const float4* __restrict__ cBox,
                                                const unsigned* __restrict__ meta,
                                                float4* __restrict__ oBox,
                                                float* __restrict__ oArea) {
    int k = blockIdx.x * 256 + threadIdx.x;
    float mc = __uint_as_float(meta[8]) + 1.0f;
    float off = (float)cLab[k] * mc;
    float4 b = cBox[k];
    float4 ob;
    ob.x = b.x + off; ob.y = b.y + off; ob.z = b.z + off; ob.w = b.w + off;
    oBox[k] = ob;
    oArea[k] = fmaxf(ob.z - ob.x, 0.f) * fmaxf(ob.w - ob.y, 0.f);
}

// ---------- 10: suppression bitmask M[i][w] : bit b set iff j=w*64+b > i and iou(i,j) > thr ----------
__global__ __launch_bounds__(256) void k_mask(const float4* __restrict__ oBox,
                                              const float* __restrict__ oArea,
                                              unsigned long long* __restrict__ M) {
    int w = threadIdx.x;                       // 0..63 word
    int i = blockIdx.x * 4 + threadIdx.y;      // row
    float4 bi = oBox[i];
    float ai = oArea[i];
    unsigned long long bits = 0ull;
    int j0 = w << 6;
    for (int b = 0; b < 64; ++b) {
        int j = j0 + b;
        float4 bj = oBox[j];
        float aj = oArea[j];
        float ix1 = fmaxf(bi.x, bj.x), iy1 = fmaxf(bi.y, bj.y);
        float ix2 = fminf(bi.z, bj.z), iy2 = fminf(bi.w, bj.w);
        float inter = fmaxf(ix2 - ix1, 0.f) * fmaxf(iy2 - iy1, 0.f);
        float uni = ai + aj - inter;
        float iou = inter / fmaxf(uni, 1e-9f);
        if ((j > i) & (iou > IOUT)) bits |= (1ull << b);
    }
    M[(long)i * 64 + w] = bits;
}

// ---------- 11: exact greedy NMS, single wave, state in registers (lane w owns word w) ----------
__global__ __launch_bounds__(64) void k_nms(const unsigned long long* __restrict__ M,
                                            const float* __restrict__ cScore,
                                            unsigned long long* __restrict__ keepW) {
    int lane = threadIdx.x;
    unsigned S_lo = 0u, S_hi = 0u;  // suppressed bits for this lane's word
    int base0 = lane << 6;
    for (int b = 0; b < 64; ++b) {
        float sc = cScore[base0 + b];
        if (!(sc > CONF)) {
            if (b < 32) S_lo |= (1u << b);
            else        S_hi |= (1u << (b - 32));
        }
    }
    unsigned long long r[16];
#pragma unroll
    for (int u = 0; u < 16; ++u) r[u] = M[(long)u * 64 + lane];
    for (int base = 0; base < TOPK; base += 16) {
#pragma unroll
        for (int u = 0; u < 16; ++u) {
            int i = base + u;
            int w = i >> 6, b = i & 63;
            unsigned sl = (unsigned)__builtin_amdgcn_readlane((int)S_lo, w);
            unsigned sh = (unsigned)__builtin_amdgcn_readlane((int)S_hi, w);
            unsigned word = (b < 32) ? sl : sh;
            unsigned bit = (word >> (b & 31)) & 1u;
            unsigned long long row = r[u];
            int nxt = i + 16;
            if (nxt < TOPK) r[u] = M[(long)nxt * 64 + lane];  // prefetch 16 ahead
            if (!bit) {  // row i kept -> suppress its conflicts
                S_lo |= (unsigned)row;
                S_hi |= (unsigned)(row >> 32);
            }
        }
    }
    unsigned long long S = ((unsigned long long)S_hi << 32) | S_lo;
    keepW[lane] = ~S;
}

// ---------- 12: finalize: rank kept, rescale boxes, emit outputs ----------
__global__ __launch_bounds__(256) void k_final(const unsigned long long* __restrict__ keepW,
                                               const float* __restrict__ cScore,
                                               const float4* __restrict__ cBox,
                                               const int* __restrict__ cIdx,
                                               const float* __restrict__ pred,
                                               const int* __restrict__ img,
                                               const int* __restrict__ inp,
                                               float* __restrict__ out,
                                               int out_size) {
    __shared__ int sel[MAXDET];
    __shared__ int nsel;
    int t = threadIdx.x;
    for (int i = t; i < out_size; i += 256) out[i] = 0.f;
    if (t == 0) nsel = 0;
    __syncthreads();
    if (t < 64) {
        unsigned long long kw = keepW[t];
        int cnt = __popcll(kw);
        int incl = cnt;
        for (int off = 1; off < 64; off <<= 1) {
            int v = __shfl_up(incl, off);
            if (t >= off) incl += v;
        }
        int rk = incl - cnt;
        if (t == 63) nsel = (incl < MAXDET) ? incl : MAXDET;
        unsigned long long m = kw;
        while (m) {
            int b = __ffsll((unsigned long long)m) - 1;
            m &= m - 1;
            if (rk < MAXDET) sel[rk] = (t << 6) + b;
            ++rk;
        }
    }
    __syncthreads();
    int nk = nsel;
    // image params — robust to int64-passed-as-int32 (second 32-bit word would be 0)
    int ih_i = img[0], iw_i = img[1];
    int nh_i = inp[0], nw_i = inp[1];
    if (iw_i == 0) iw_i = img[2];
    if (nw_i == 0) nw_i = inp[2];
    float ih = (float)ih_i, iw = (float)iw_i;
    float nh = (float)nh_i, nw = (float)nw_i;
    float gain = fminf(nh / ih, nw / iw);
    float pad0 = (nh - ih * gain) * 0.5f;
    float pad1 = (nw - iw * gain) * 0.5f;
    for (int o = t; o < nk; o += 256) {
        int k = sel[o];
        float4 b = cBox[k];
        float x1 = fminf(fmaxf((b.x - pad1) / gain, 0.f), iw);
        float y1 = fminf(fmaxf((b.y - pad0) / gain, 0.f), ih);
        float x2 = fminf(fmaxf((b.z - pad1) / gain, 0.f), iw);
        float y2 = fminf(fmaxf((b.w - pad0) / gain, 0.f), ih);
        out[o * 4 + 0] = (x1 + x2) * 0.5f / iw;
        out[o * 4 + 1] = (y1 + y2) * 0.5f / ih;
        out[o * 4 + 2] = (x2 - x1) / iw;
        out[o * 4 + 3] = (y2 - y1) / ih;
        out[4 * MAXDET + o] = cScore[k];
    }
    for (int p = t; p < nk * N_CLS; p += 256) {
        int o = p / N_CLS, c = p - o * N_CLS;
        int a = cIdx[sel[o]];
        out[5 * MAXDET + p] = pred[(long)a * 85 + 5 + c];
    }
}

extern "C" void kernel_launch(void* const* d_in, const int* in_sizes, int n_in,
                              void* d_out, int out_size, void* d_ws, size_t ws_size,
                              hipStream_t stream) {
    const float* pred = (const float*)d_in[0];
    const int* img = (const int*)d_in[1];
    const int* inp = (const int*)d_in[2];
    float* out = (float*)d_out;
    unsigned char* W = (unsigned char*)d_ws;

    unsigned* hist                = (unsigned*)(W + 0);                // 262144 B
    unsigned* meta                = (unsigned*)(W + 262144);           // 256 B
    unsigned* ord                 = (unsigned*)(W + 262400);           // 480000 B
    int* lab                      = (int*)(W + 742400);                // 480000 B
    float4* box                   = (float4*)(W + 1222400);            // 1920000 B (16B aligned)
    unsigned long long* keys      = (unsigned long long*)(W + 3142400);// 32768 B
    unsigned* eq                  = (unsigned*)(W + 3175168);          // 16384 B
    int* cIdx                     = (int*)(W + 3191552);               // 16384 B
    float* cScore                 = (float*)(W + 3207936);             // 16384 B
    int* cLab                     = (int*)(W + 3224320);               // 16384 B
    float4* cBox                  = (float4*)(W + 3240704);            // 65536 B
    float4* oBox                  = (float4*)(W + 3306240);            // 65536 B
    float* oArea                  = (float*)(W + 3371776);             // 16384 B
    unsigned long long* M         = (unsigned long long*)(W + 3388160);// 2097152 B
    unsigned long long* keepW     = (unsigned long long*)(W + 5485312);// 512 B

    int nb = (N_ANCH + 255) / 256;
    k_zero<<<64, 1024, 0, stream>>>(hist, meta);
    k_decode<<<nb, 256, 0, stream>>>(pred, ord, lab, box, hist);
    k_select<<<1, 1024, 0, stream>>>(hist, meta, 0);
    k_hist2<<<nb, 256, 0, stream>>>(ord, meta, hist);
    k_select<<<1, 1024, 0, stream>>>(hist, meta, 1);
    k_compact<<<nb, 256, 0, stream>>>(ord, meta, keys, eq);
    k_eqsort<<<1, 1024, 0, stream>>>(eq, meta, keys);
    k_sort<<<1, 1024, 0, stream>>>(keys);
    k_gather<<<16, 256, 0, stream>>>(keys, lab, box, cIdx, cScore, cLab, cBox, meta);
    k_offbox<<<16, 256, 0, stream>>>(cLab, cBox, meta, oBox, oArea);
    k_mask<<<1024, dim3(64, 4), 0, stream>>>(oBox, oArea, M);
    k_nms<<<1, 64, 0, stream>>>(M, cScore, keepW);
    k_final<<<1, 256, 0, stream>>>(keepW, cScore, cBox, cIdx, pred, img, inp, out, out_size);
}

// Round 2
// 801.091 us; speedup vs baseline: 2.3282x; 2.3282x over previous
//
#include <hip/hip_runtime.h>
#include <math.h>

#define N_ANCH 120000
#define N_CLS  80
#define TOPK   4096
#define MAXDET 100
#define CONF   0.25f
#define IOUT   0.4f

// ---------- helpers ----------
__device__ __forceinline__ unsigned f2ord(float f) {
    unsigned u = __float_as_uint(f);
    return (u & 0x80000000u) ? ~u : (u | 0x80000000u);
}
__device__ __forceinline__ float ord2f(unsigned o) {
    unsigned u = (o & 0x80000000u) ? (o & 0x7FFFFFFFu) : ~o;
    return __uint_as_float(u);
}

// ---------- 0: zero hist + meta ----------
__global__ __launch_bounds__(1024) void k_zero(unsigned* hist, unsigned* meta) {
    int i = blockIdx.x * 1024 + threadIdx.x;
    if (i < 65536) hist[i] = 0u;
    if (i < 64) meta[i] = 0u;
}

// ---------- 1: decode anchors + histogram round 1 (bits 31:16 of ordered score) ----------
__global__ __launch_bounds__(256) void k_decode(const float* __restrict__ pred,
                                                unsigned* __restrict__ ord,
                                                int* __restrict__ lab,
                                                float4* __restrict__ box,
                                                unsigned* __restrict__ hist) {
    int a = blockIdx.x * 256 + threadIdx.x;
    if (a >= N_ANCH) return;
    const float* p = pred + (long)a * 85;
    float x = p[0], y = p[1], w = p[2], h = p[3], obj = p[4];
    float best = p[5];
    int bl = 0;
    for (int c = 1; c < N_CLS; ++c) {
        float v = p[5 + c];
        if (v > best) { best = v; bl = c; }   // first-max (argmax) semantics
    }
    float sc = obj * best;
    float hw = w * 0.5f, hh = h * 0.5f;
    float4 b;
    b.x = x - hw; b.y = y - hh; b.z = x + hw; b.w = y + hh;
    bool valid = sc > CONF;
    float m = valid ? sc : -INFINITY;
    unsigned o = f2ord(m);
    ord[a] = o;
    lab[a] = bl;
    box[a] = b;
    atomicAdd(&hist[o >> 16], 1u);
}

// ---------- 2/4: histogram select (suffix scan over 65536 bins) ----------
__global__ __launch_bounds__(1024) void k_select(unsigned* hist, unsigned* meta, int mode) {
    __shared__ unsigned part[1024];
    int t = threadIdx.x;
    unsigned target = (mode == 0) ? (unsigned)TOPK : meta[2];
    int base = t * 64;
    unsigned local = 0;
    for (int i = 0; i < 64; ++i) local += hist[base + i];
    part[t] = local;
    __syncthreads();
    for (int off = 1; off < 1024; off <<= 1) {
        unsigned v = (t + off < 1024) ? part[t + off] : 0u;
        __syncthreads();
        part[t] += v;
        __syncthreads();
    }
    unsigned incl = part[t];
    unsigned after = (t + 1 < 1024) ? part[t + 1] : 0u;
    if (after < target && incl >= target) {
        unsigned run = after;
        for (int i = 63; i >= 0; --i) {
            unsigned c = hist[base + i];
            if (run + c >= target) {
                if (mode == 0) {
                    meta[0] = (unsigned)(base + i);
                    meta[1] = run;
                    meta[2] = (unsigned)TOPK - run;
                } else {
                    meta[3] = (meta[0] << 16) | (unsigned)(base + i);
                    meta[4] = meta[1] + run;
                    meta[5] = meta[2] - run;
                }
                break;
            }
            run += c;
        }
    }
    if (mode == 0) {
        for (int i = 0; i < 64; ++i) hist[base + i] = 0u;
    }
}

// ---------- 3: histogram round 2 ----------
__global__ __launch_bounds__(256) void k_hist2(const unsigned* __restrict__ ord,
                                               const unsigned* __restrict__ meta,
                                               unsigned* __restrict__ hist) {
    int a = blockIdx.x * 256 + threadIdx.x;
    if (a >= N_ANCH) return;
    unsigned o = ord[a];
    if ((o >> 16) == meta[0]) atomicAdd(&hist[o & 0xFFFFu], 1u);
}

// ---------- 5: compact ----------
__global__ __launch_bounds__(256) void k_compact(const unsigned* __restrict__ ord,
                                                 unsigned* meta,
                                                 unsigned long long* __restrict__ keys,
                                                 unsigned* __restrict__ eq) {
    int a = blockIdx.x * 256 + threadIdx.x;
    if (a >= N_ANCH) return;
    unsigned o = ord[a];
    unsigned T = meta[3];
    if (o > T) {
        unsigned p = atomicAdd(&meta[6], 1u);
        keys[p] = ((unsigned long long)o << 32) | (unsigned)(~(unsigned)a);
    } else if (o == T) {
        unsigned p = atomicAdd(&meta[7], 1u);
        if (p < TOPK) eq[p] = (unsigned)a;
    }
}

// ---------- 6: sort tie indices ascending, append remEq smallest ----------
__global__ __launch_bounds__(1024) void k_eqsort(const unsigned* __restrict__ eq,
                                                 unsigned* meta,
                                                 unsigned long long* keys) {
    __shared__ unsigned s[TOPK];
    int t = threadIdx.x;
    unsigned n = meta[7]; if (n > TOPK) n = TOPK;
    unsigned remEq = meta[5];
    unsigned baseA = meta[4];
    unsigned T = meta[3];
    for (int i = t; i < TOPK; i += 1024) s[i] = (i < (int)n) ? eq[i] : 0xFFFFFFFFu;
    __syncthreads();
    for (int k = 2; k <= TOPK; k <<= 1)
        for (int j = k >> 1; j > 0; j >>= 1) {
            for (int idx = t; idx < TOPK; idx += 1024) {
                int ixj = idx ^ j;
                if (ixj > idx) {
                    unsigned a = s[idx], b = s[ixj];
                    bool asc = ((idx & k) == 0);
                    bool sw = asc ? (a > b) : (a < b);
                    if (sw) { s[idx] = b; s[ixj] = a; }
                }
            }
            __syncthreads();
        }
    for (unsigned r = t; r < remEq; r += 1024)
        keys[baseA + r] = ((unsigned long long)T << 32) | (unsigned)(~s[r]);
}

// ---------- 7: bitonic sort 4096 keys descending ----------
__global__ __launch_bounds__(1024) void k_sort(unsigned long long* keys) {
    __shared__ unsigned long long s[TOPK];
    int t = threadIdx.x;
    for (int i = t; i < TOPK; i += 1024) s[i] = keys[i];
    __syncthreads();
    for (int k = 2; k <= TOPK; k <<= 1)
        for (int j = k >> 1; j > 0; j >>= 1) {
            for (int idx = t; idx < TOPK; idx += 1024) {
                int ixj = idx ^ j;
                if (ixj > idx) {
                    unsigned long long a = s[idx], b = s[ixj];
                    bool desc = ((idx & k) == 0);
                    bool sw = desc ? (a < b) : (a > b);
                    if (sw) { s[idx] = b; s[ixj] = a; }
                }
            }
            __syncthreads();
        }
    for (int i = t; i < TOPK; i += 1024) keys[i] = s[i];
}

// ---------- 8: gather + max_coord ----------
__global__ __launch_bounds__(256) void k_gather(const unsigned long long* __restrict__ keys,
                                                const int* __restrict__ lab,
                                                const float4* __restrict__ box,
                                                int* __restrict__ cIdx,
                                                float* __restrict__ cScore,
                                                int* __restrict__ cLab,
                                                float4* __restrict__ cBox,
                                                unsigned* meta) {
    int k = blockIdx.x * 256 + threadIdx.x;
    unsigned long long key = keys[k];
    unsigned o = (unsigned)(key >> 32);
    unsigned a = ~(unsigned)(key & 0xFFFFFFFFu);
    float sc = ord2f(o);
    cIdx[k] = (int)a;
    cScore[k] = sc;
    cLab[k] = lab[a];
    float4 b = box[a];
    cBox[k] = b;
    if (sc > CONF) {
        if (b.x > 0.f) atomicMax(&meta[8], __float_as_uint(b.x));
        if (b.y > 0.f) atomicMax(&meta[8], __float_as_uint(b.y));
        if (b.z > 0.f) atomicMax(&meta[8], __float_as_uint(b.z));
        if (b.w > 0.f) atomicMax(&meta[8], __float_as_uint(b.w));
    }
}

// ---------- 9: offset boxes + areas ----------
__global__ __launch_bounds__(256) void k_offbox(const int* __restrict__ cLab,
                                                const float4* __restrict__ cBox,
                                                const unsigned* __restrict__ meta,
                                                float4* __restrict__ oBox,
                                                float* __restrict__ oArea) {
    int k = blockIdx.x * 256 + threadIdx.x;
    float mc = __uint_as_float(meta[8]) + 1.0f;
    float off = (float)cLab[k] * mc;
    float4 b = cBox[k];
    float4 ob;
    ob.x = b.x + off; ob.y = b.y + off; ob.z = b.z + off; ob.w = b.w + off;
    oBox[k] = ob;
    oArea[k] = fmaxf(ob.z - ob.x, 0.f) * fmaxf(ob.w - ob.y, 0.f);
}

// ---------- 10: suppression bitmask ----------
__global__ __launch_bounds__(256) void k_mask(const float4* __restrict__ oBox,
                                              const float* __restrict__ oArea,
                                              unsigned long long* __restrict__ M) {
    int w = threadIdx.x;
    int i = blockIdx.x * 4 + threadIdx.y;
    float4 bi = oBox[i];
    float ai = oArea[i];
    unsigned long long bits = 0ull;
    int j0 = w << 6;
    for (int b = 0; b < 64; ++b) {
        int j = j0 + b;
        float4 bj = oBox[j];
        float aj = oArea[j];
        float ix1 = fmaxf(bi.x, bj.x), iy1 = fmaxf(bi.y, bj.y);
        float ix2 = fminf(bi.z, bj.z), iy2 = fminf(bi.w, bj.w);
        float inter = fmaxf(ix2 - ix1, 0.f) * fmaxf(iy2 - iy1, 0.f);
        float uni = ai + aj - inter;
        float iou = inter / fmaxf(uni, 1e-9f);
        if ((j > i) & (iou > IOUT)) bits |= (1ull << b);
    }
    M[(long)i * 64 + w] = bits;
}

// ---------- 11: greedy NMS, single wave, 64x64 tiled ----------
// State: lane w owns suppression word w (columns 64w..64w+63), in register S.
// Per tile t (rows 64t..64t+63):
//   pass A: resolve intra-tile keeps using only the diagonal 64x64 block
//           (register readlane chain, no memory on the critical path);
//   pass B: branchless OR of all 64 rows (coalesced 512B loads) under keep mask.
__global__ __launch_bounds__(64) void k_nms(const unsigned long long* __restrict__ M,
                                            const float* __restrict__ cScore,
                                            unsigned long long* __restrict__ keepW) {
    int lane = threadIdx.x;
    unsigned long long S = 0ull;   // suppressed|invalid bits for this lane's word
    int base0 = lane << 6;
#pragma unroll 8
    for (int b = 0; b < 64; ++b) {
        float sc = cScore[base0 + b];
        if (!(sc > CONF)) S |= (1ull << b);
    }
    // prefetch diagonal word for tile 0: row `lane`, word 0
    unsigned long long d = M[(long)lane * 64 + 0];
    for (int t = 0; t < 64; ++t) {
        unsigned long long dcur = d;
        if (t + 1 < 64) d = M[(long)((t + 1) * 64 + lane) * 64 + (t + 1)];  // prefetch next diag
        // broadcast suppression word t (owned by lane t)
        unsigned s_lo = (unsigned)__builtin_amdgcn_readlane((int)(unsigned)S, t);
        unsigned s_hi = (unsigned)__builtin_amdgcn_readlane((int)(unsigned)(S >> 32), t);
        unsigned long long s_tile = ((unsigned long long)s_hi << 32) | s_lo;
        // intra-tile greedy resolution: bit b of s_tile decides row 64t+b.
        // readlanes are independent of s_tile -> hoisted; chain is ~6 VALU ops/step.
#pragma unroll
        for (int b = 0; b < 64; ++b) {
            unsigned rl = (unsigned)__builtin_amdgcn_readlane((int)(unsigned)dcur, b);
            unsigned rh = (unsigned)__builtin_amdgcn_readlane((int)(unsigned)(dcur >> 32), b);
            unsigned long long row = ((unsigned long long)rh << 32) | rl;
            unsigned long long mask = 0ull - (((~s_tile) >> b) & 1ull);  // all-ones if row kept
            s_tile |= row & mask;
        }
        unsigned long long kt = ~s_tile;  // keep bits for this tile's rows
        // apply kept rows' full masks; loads independent (pipelined), OR is branchless
        const unsigned long long* Mrow = M + (long)(t << 6) * 64 + lane;
#pragma unroll 16
        for (int b = 0; b < 64; ++b) {
            unsigned long long row = Mrow[(long)b * 64];
            unsigned long long mask = 0ull - ((kt >> b) & 1ull);
            S |= row & mask;
        }
    }
    keepW[lane] = ~S;
}

// ---------- 12: finalize ----------
__global__ __launch_bounds__(256) void k_final(const unsigned long long* __restrict__ keepW,
                                               const float* __restrict__ cScore,
                                               const float4* __restrict__ cBox,
                                               const int* __restrict__ cIdx,
                                               const float* __restrict__ pred,
                                               const int* __restrict__ img,
                                               const int* __restrict__ inp,
                                               float* __restrict__ out,
                                               int out_size) {
    __shared__ int sel[MAXDET];
    __shared__ int nsel;
    int t = threadIdx.x;
    for (int i = t; i < out_size; i += 256) out[i] = 0.f;
    if (t == 0) nsel = 0;
    __syncthreads();
    if (t < 64) {
        unsigned long long kw = keepW[t];
        int cnt = __popcll(kw);
        int incl = cnt;
        for (int off = 1; off < 64; off <<= 1) {
            int v = __shfl_up(incl, off);
            if (t >= off) incl += v;
        }
        int rk = incl - cnt;
        if (t == 63) nsel = (incl < MAXDET) ? incl : MAXDET;
        unsigned long long m = kw;
        while (m) {
            int b = __ffsll((unsigned long long)m) - 1;
            m &= m - 1;
            if (rk < MAXDET) sel[rk] = (t << 6) + b;
            ++rk;
        }
    }
    __syncthreads();
    int nk = nsel;
    int ih_i = img[0], iw_i = img[1];
    int nh_i = inp[0], nw_i = inp[1];
    if (iw_i == 0) iw_i = img[2];
    if (nw_i == 0) nw_i = inp[2];
    float ih = (float)ih_i, iw = (float)iw_i;
    float nh = (float)nh_i, nw = (float)nw_i;
    float gain = fminf(nh / ih, nw / iw);
    float pad0 = (nh - ih * gain) * 0.5f;
    float pad1 = (nw - iw * gain) * 0.5f;
    for (int o = t; o < nk; o += 256) {
        int k = sel[o];
        float4 b = cBox[k];
        float x1 = fminf(fmaxf((b.x - pad1) / gain, 0.f), iw);
        float y1 = fminf(fmaxf((b.y - pad0) / gain, 0.f), ih);
        float x2 = fminf(fmaxf((b.z - pad1) / gain, 0.f), iw);
        float y2 = fminf(fmaxf((b.w - pad0) / gain, 0.f), ih);
        out[o * 4 + 0] = (x1 + x2) * 0.5f / iw;
        out[o * 4 + 1] = (y1 + y2) * 0.5f / ih;
        out[o * 4 + 2] = (x2 - x1) / iw;
        out[o * 4 + 3] = (y2 - y1) / ih;
        out[4 * MAXDET + o] = cScore[k];
    }
    for (int p = t; p < nk * N_CLS; p += 256) {
        int o = p / N_CLS, c = p - o * N_CLS;
        int a = cIdx[sel[o]];
        out[5 * MAXDET + p] = pred[(long)a * 85 + 5 + c];
    }
}

extern "C" void kernel_launch(void* const* d_in, const int* in_sizes, int n_in,
                              void* d_out, int out_size, void* d_ws, size_t ws_size,
                              hipStream_t stream) {
    const float* pred = (const float*)d_in[0];
    const int* img = (const int*)d_in[1];
    const int* inp = (const int*)d_in[2];
    float* out = (float*)d_out;
    unsigned char* W = (unsigned char*)d_ws;

    unsigned* hist                = (unsigned*)(W + 0);                // 262144 B
    unsigned* meta                = (unsigned*)(W + 262144);           // 256 B
    unsigned* ord                 = (unsigned*)(W + 262400);           // 480000 B
    int* lab                      = (int*)(W + 742400);                // 480000 B
    float4* box                   = (float4*)(W + 1222400);            // 1920000 B
    unsigned long long* keys      = (unsigned long long*)(W + 3142400);// 32768 B
    unsigned* eq                  = (unsigned*)(W + 3175168);          // 16384 B
    int* cIdx                     = (int*)(W + 3191552);               // 16384 B
    float* cScore                 = (float*)(W + 3207936);             // 16384 B
    int* cLab                     = (int*)(W + 3224320);               // 16384 B
    float4* cBox                  = (float4*)(W + 3240704);            // 65536 B
    float4* oBox                  = (float4*)(W + 3306240);            // 65536 B
    float* oArea                  = (float*)(W + 3371776);             // 16384 B
    unsigned long long* M         = (unsigned long long*)(W + 3388160);// 2097152 B
    unsigned long long* keepW     = (unsigned long long*)(W + 5485312);// 512 B

    int nb = (N_ANCH + 255) / 256;
    k_zero<<<64, 1024, 0, stream>>>(hist, meta);
    k_decode<<<nb, 256, 0, stream>>>(pred, ord, lab, box, hist);
    k_select<<<1, 1024, 0, stream>>>(hist, meta, 0);
    k_hist2<<<nb, 256, 0, stream>>>(ord, meta, hist);
    k_select<<<1, 1024, 0, stream>>>(hist, meta, 1);
    k_compact<<<nb, 256, 0, stream>>>(ord, meta, keys, eq);
    k_eqsort<<<1, 1024, 0, stream>>>(eq, meta, keys);
    k_sort<<<1, 1024, 0, stream>>>(keys);
    k_gather<<<16, 256, 0, stream>>>(keys, lab, box, cIdx, cScore, cLab, cBox, meta);
    k_offbox<<<16, 256, 0, stream>>>(cLab, cBox, meta, oBox, oArea);
    k_mask<<<1024, dim3(64, 4), 0, stream>>>(oBox, oArea, M);
    k_nms<<<1, 64, 0, stream>>>(M, cScore, keepW);
    k_final<<<1, 256, 0, stream>>>(keepW, cScore, cBox, cIdx, pred, img, inp, out, out_size);
}

// Round 3
// 747.364 us; speedup vs baseline: 2.4956x; 1.0719x over previous
//
#include <hip/hip_runtime.h>
#include <math.h>

#define N_ANCH 120000
#define N_CLS  80
#define TOPK   4096
#define MAXDET 100
#define CONF   0.25f
#define IOUT   0.4f
#define DBLK   128   // anchors per decode block

// ---------- helpers ----------
__device__ __forceinline__ unsigned f2ord(float f) {
    unsigned u = __float_as_uint(f);
    return (u & 0x80000000u) ? ~u : (u | 0x80000000u);
}
__device__ __forceinline__ float ord2f(unsigned o) {
    unsigned u = (o & 0x80000000u) ? (o & 0x7FFFFFFFu) : ~o;
    return __uint_as_float(u);
}

// ---------- 0: zero hist + meta ----------
__global__ __launch_bounds__(1024) void k_zero(unsigned* hist, unsigned* meta) {
    int i = blockIdx.x * 1024 + threadIdx.x;
    if (i < 65536) hist[i] = 0u;
    if (i < 64) meta[i] = 0u;
}

// ---------- 1: decode anchors (LDS-staged, coalesced) + histogram round 1 ----------
__global__ __launch_bounds__(DBLK) void k_decode(const float* __restrict__ pred,
                                                 unsigned* __restrict__ ord,
                                                 int* __restrict__ lab,
                                                 float4* __restrict__ box,
                                                 unsigned* __restrict__ hist) {
    __shared__ float s[DBLK * 85];   // 43520 B
    int blk = blockIdx.x;
    long basef = (long)blk * (DBLK * 85);
    long remf = (long)N_ANCH * 85 - basef;
    int nf = (int)(remf < (long)(DBLK * 85) ? remf : (long)(DBLK * 85));
    int tot4 = nf >> 2;  // all block float-counts are multiples of 4
    const float4* g4 = (const float4*)(pred + basef);  // 16B aligned: basef*4 % 16 == 0
    float4* s4 = (float4*)s;
    for (int i = threadIdx.x; i < tot4; i += DBLK) s4[i] = g4[i];
    __syncthreads();
    int a = blk * DBLK + threadIdx.x;
    if (a >= N_ANCH) return;
    const float* p = s + threadIdx.x * 85;  // bank = (21*lane + c) % 32 -> 2-way, free
    float x = p[0], y = p[1], w = p[2], h = p[3], obj = p[4];
    float best = p[5];
    int bl = 0;
    for (int c = 1; c < N_CLS; ++c) {
        float v = p[5 + c];
        if (v > best) { best = v; bl = c; }   // first-max (argmax) semantics
    }
    float sc = obj * best;
    float hw = w * 0.5f, hh = h * 0.5f;
    float4 b;
    b.x = x - hw; b.y = y - hh; b.z = x + hw; b.w = y + hh;
    bool valid = sc > CONF;
    float m = valid ? sc : -INFINITY;
    unsigned o = f2ord(m);
    ord[a] = o;
    lab[a] = bl;
    box[a] = b;
    atomicAdd(&hist[o >> 16], 1u);
}

// ---------- 2/4: histogram select (suffix scan over 65536 bins) ----------
__global__ __launch_bounds__(1024) void k_select(unsigned* hist, unsigned* meta, int mode) {
    __shared__ unsigned part[1024];
    int t = threadIdx.x;
    unsigned target = (mode == 0) ? (unsigned)TOPK : meta[2];
    int base = t * 64;
    unsigned local = 0;
    for (int i = 0; i < 64; ++i) local += hist[base + i];
    part[t] = local;
    __syncthreads();
    for (int off = 1; off < 1024; off <<= 1) {
        unsigned v = (t + off < 1024) ? part[t + off] : 0u;
        __syncthreads();
        part[t] += v;
        __syncthreads();
    }
    unsigned incl = part[t];
    unsigned after = (t + 1 < 1024) ? part[t + 1] : 0u;
    if (after < target && incl >= target) {
        unsigned c64[64];
#pragma unroll
        for (int i = 0; i < 64; ++i) c64[i] = hist[base + i];  // independent, pipelined
        unsigned run = after;
        for (int i = 63; i >= 0; --i) {
            unsigned c = c64[i];
            if (run + c >= target) {
                if (mode == 0) {
                    meta[0] = (unsigned)(base + i);
                    meta[1] = run;
                    meta[2] = (unsigned)TOPK - run;
                } else {
                    meta[3] = (meta[0] << 16) | (unsigned)(base + i);
                    meta[4] = meta[1] + run;
                    meta[5] = meta[2] - run;
                }
                break;
            }
            run += c;
        }
    }
    if (mode == 0) {
        for (int i = 0; i < 64; ++i) hist[base + i] = 0u;
    }
}

// ---------- 3: histogram round 2 ----------
__global__ __launch_bounds__(256) void k_hist2(const unsigned* __restrict__ ord,
                                               const unsigned* __restrict__ meta,
                                               unsigned* __restrict__ hist) {
    int a = blockIdx.x * 256 + threadIdx.x;
    if (a >= N_ANCH) return;
    unsigned o = ord[a];
    if ((o >> 16) == meta[0]) atomicAdd(&hist[o & 0xFFFFu], 1u);
}

// ---------- 5: compact ----------
__global__ __launch_bounds__(256) void k_compact(const unsigned* __restrict__ ord,
                                                 unsigned* meta,
                                                 unsigned long long* __restrict__ keys,
                                                 unsigned* __restrict__ eq) {
    int a = blockIdx.x * 256 + threadIdx.x;
    if (a >= N_ANCH) return;
    unsigned o = ord[a];
    unsigned T = meta[3];
    if (o > T) {
        unsigned p = atomicAdd(&meta[6], 1u);
        keys[p] = ((unsigned long long)o << 32) | (unsigned)(~(unsigned)a);
    } else if (o == T) {
        unsigned p = atomicAdd(&meta[7], 1u);
        if (p < TOPK) eq[p] = (unsigned)a;
    }
}

// ---------- 6: tie handling. Membership = remEq smallest tie indices.
// Order among equal-T keys is irrelevant (k_sort orders by ~index), so only
// sort when we must SELECT a strict subset (n > remEq); else straight copy.
__global__ __launch_bounds__(1024) void k_eqsort(const unsigned* __restrict__ eq,
                                                 unsigned* meta,
                                                 unsigned long long* keys) {
    __shared__ unsigned s[TOPK];
    int t = threadIdx.x;
    unsigned n = meta[7]; if (n > TOPK) n = TOPK;
    unsigned remEq = meta[5];
    unsigned baseA = meta[4];
    unsigned T = meta[3];
    if (remEq == 0) return;
    if (n > remEq) {
        unsigned m = 1; while (m < n) m <<= 1;
        for (unsigned i = t; i < m; i += 1024) s[i] = (i < n) ? eq[i] : 0xFFFFFFFFu;
        __syncthreads();
        for (unsigned k = 2; k <= m; k <<= 1)
            for (unsigned j = k >> 1; j > 0; j >>= 1) {
                for (unsigned idx = t; idx < m; idx += 1024) {
                    unsigned ixj = idx ^ j;
                    if (ixj > idx) {
                        unsigned a = s[idx], b = s[ixj];
                        bool asc = ((idx & k) == 0);
                        bool sw = asc ? (a > b) : (a < b);
                        if (sw) { s[idx] = b; s[ixj] = a; }
                    }
                }
                __syncthreads();
            }
        for (unsigned r = t; r < remEq; r += 1024)
            keys[baseA + r] = ((unsigned long long)T << 32) | (unsigned)(~s[r]);
    } else {
        for (unsigned r = t; r < remEq; r += 1024)
            keys[baseA + r] = ((unsigned long long)T << 32) | (unsigned)(~eq[r]);
    }
}

// ---------- 7: bitonic sort 4096 keys descending ----------
__global__ __launch_bounds__(1024) void k_sort(unsigned long long* keys) {
    __shared__ unsigned long long s[TOPK];
    int t = threadIdx.x;
    for (int i = t; i < TOPK; i += 1024) s[i] = keys[i];
    __syncthreads();
    for (int k = 2; k <= TOPK; k <<= 1)
        for (int j = k >> 1; j > 0; j >>= 1) {
            for (int idx = t; idx < TOPK; idx += 1024) {
                int ixj = idx ^ j;
                if (ixj > idx) {
                    unsigned long long a = s[idx], b = s[ixj];
                    bool desc = ((idx & k) == 0);
                    bool sw = desc ? (a < b) : (a > b);
                    if (sw) { s[idx] = b; s[ixj] = a; }
                }
            }
            __syncthreads();
        }
    for (int i = t; i < TOPK; i += 1024) keys[i] = s[i];
}

// ---------- 8: gather + max_coord ----------
__global__ __launch_bounds__(256) void k_gather(const unsigned long long* __restrict__ keys,
                                                const int* __restrict__ lab,
                                                const float4* __restrict__ box,
                                                int* __restrict__ cIdx,
                                                float* __restrict__ cScore,
                                                int* __restrict__ cLab,
                                                float4* __restrict__ cBox,
                                                unsigned* meta) {
    int k = blockIdx.x * 256 + threadIdx.x;
    unsigned long long key = keys[k];
    unsigned o = (unsigned)(key >> 32);
    unsigned a = ~(unsigned)(key & 0xFFFFFFFFu);
    float sc = ord2f(o);
    cIdx[k] = (int)a;
    cScore[k] = sc;
    cLab[k] = lab[a];
    float4 b = box[a];
    cBox[k] = b;
    if (sc > CONF) {
        if (b.x > 0.f) atomicMax(&meta[8], __float_as_uint(b.x));
        if (b.y > 0.f) atomicMax(&meta[8], __float_as_uint(b.y));
        if (b.z > 0.f) atomicMax(&meta[8], __float_as_uint(b.z));
        if (b.w > 0.f) atomicMax(&meta[8], __float_as_uint(b.w));
    }
}

// ---------- 9: offset boxes + areas ----------
__global__ __launch_bounds__(256) void k_offbox(const int* __restrict__ cLab,
                                                const float4* __restrict__ cBox,
                                                const unsigned* __restrict__ meta,
                                                float4* __restrict__ oBox,
                                                float* __restrict__ oArea) {
    int k = blockIdx.x * 256 + threadIdx.x;
    float mc = __uint_as_float(meta[8]) + 1.0f;
    float off = (float)cLab[k] * mc;
    float4 b = cBox[k];
    float4 ob;
    ob.x = b.x + off; ob.y = b.y + off; ob.z = b.z + off; ob.w = b.w + off;
    oBox[k] = ob;
    oArea[k] = fmaxf(ob.z - ob.x, 0.f) * fmaxf(ob.w - ob.y, 0.f);
}

// ---------- 10: suppression bitmask ----------
__global__ __launch_bounds__(256) void k_mask(const float4* __restrict__ oBox,
                                              const float* __restrict__ oArea,
                                              unsigned long long* __restrict__ M) {
    int w = threadIdx.x;
    int i = blockIdx.x * 4 + threadIdx.y;
    float4 bi = oBox[i];
    float ai = oArea[i];
    unsigned long long bits = 0ull;
    int j0 = w << 6;
    for (int b = 0; b < 64; ++b) {
        int j = j0 + b;
        float4 bj = oBox[j];
        float aj = oArea[j];
        float ix1 = fmaxf(bi.x, bj.x), iy1 = fmaxf(bi.y, bj.y);
        float ix2 = fminf(bi.z, bj.z), iy2 = fminf(bi.w, bj.w);
        float inter = fmaxf(ix2 - ix1, 0.f) * fmaxf(iy2 - iy1, 0.f);
        float uni = ai + aj - inter;
        float iou = inter / fmaxf(uni, 1e-9f);
        if ((j > i) & (iou > IOUT)) bits |= (1ull << b);
    }
    M[(long)i * 64 + w] = bits;
}

// ---------- 11: greedy NMS, single wave, 64x64 tiled ----------
__global__ __launch_bounds__(64) void k_nms(const unsigned long long* __restrict__ M,
                                            const float* __restrict__ cScore,
                                            unsigned long long* __restrict__ keepW) {
    int lane = threadIdx.x;
    unsigned long long S = 0ull;
    int base0 = lane << 6;
#pragma unroll 8
    for (int b = 0; b < 64; ++b) {
        float sc = cScore[base0 + b];
        if (!(sc > CONF)) S |= (1ull << b);
    }
    unsigned long long d = M[(long)lane * 64 + 0];
    for (int t = 0; t < 64; ++t) {
        unsigned long long dcur = d;
        if (t + 1 < 64) d = M[(long)((t + 1) * 64 + lane) * 64 + (t + 1)];
        unsigned s_lo = (unsigned)__builtin_amdgcn_readlane((int)(unsigned)S, t);
        unsigned s_hi = (unsigned)__builtin_amdgcn_readlane((int)(unsigned)(S >> 32), t);
        unsigned long long s_tile = ((unsigned long long)s_hi << 32) | s_lo;
#pragma unroll
        for (int b = 0; b < 64; ++b) {
            unsigned rl = (unsigned)__builtin_amdgcn_readlane((int)(unsigned)dcur, b);
            unsigned rh = (unsigned)__builtin_amdgcn_readlane((int)(unsigned)(dcur >> 32), b);
            unsigned long long row = ((unsigned long long)rh << 32) | rl;
            unsigned long long mask = 0ull - (((~s_tile) >> b) & 1ull);
            s_tile |= row & mask;
        }
        unsigned long long kt = ~s_tile;
        const unsigned long long* Mrow = M + (long)(t << 6) * 64 + lane;
#pragma unroll 16
        for (int b = 0; b < 64; ++b) {
            unsigned long long row = Mrow[(long)b * 64];
            unsigned long long mask = 0ull - ((kt >> b) & 1ull);
            S |= row & mask;
        }
    }
    keepW[lane] = ~S;
}

// ---------- 12: finalize ----------
__global__ __launch_bounds__(256) void k_final(const unsigned long long* __restrict__ keepW,
                                               const float* __restrict__ cScore,
                                               const float4* __restrict__ cBox,
                                               const int* __restrict__ cIdx,
                                               const float* __restrict__ pred,
                                               const int* __restrict__ img,
                                               const int* __restrict__ inp,
                                               float* __restrict__ out,
                                               int out_size) {
    __shared__ int sel[MAXDET];
    __shared__ int nsel;
    int t = threadIdx.x;
    for (int i = t; i < out_size; i += 256) out[i] = 0.f;
    if (t == 0) nsel = 0;
    __syncthreads();
    if (t < 64) {
        unsigned long long kw = keepW[t];
        int cnt = __popcll(kw);
        int incl = cnt;
        for (int off = 1; off < 64; off <<= 1) {
            int v = __shfl_up(incl, off);
            if (t >= off) incl += v;
        }
        int rk = incl - cnt;
        if (t == 63) nsel = (incl < MAXDET) ? incl : MAXDET;
        unsigned long long m = kw;
        while (m) {
            int b = __ffsll((unsigned long long)m) - 1;
            m &= m - 1;
            if (rk < MAXDET) sel[rk] = (t << 6) + b;
            ++rk;
        }
    }
    __syncthreads();
    int nk = nsel;
    int ih_i = img[0], iw_i = img[1];
    int nh_i = inp[0], nw_i = inp[1];
    if (iw_i == 0) iw_i = img[2];
    if (nw_i == 0) nw_i = inp[2];
    float ih = (float)ih_i, iw = (float)iw_i;
    float nh = (float)nh_i, nw = (float)nw_i;
    float gain = fminf(nh / ih, nw / iw);
    float pad0 = (nh - ih * gain) * 0.5f;
    float pad1 = (nw - iw * gain) * 0.5f;
    for (int o = t; o < nk; o += 256) {
        int k = sel[o];
        float4 b = cBox[k];
        float x1 = fminf(fmaxf((b.x - pad1) / gain, 0.f), iw);
        float y1 = fminf(fmaxf((b.y - pad0) / gain, 0.f), ih);
        float x2 = fminf(fmaxf((b.z - pad1) / gain, 0.f), iw);
        float y2 = fminf(fmaxf((b.w - pad0) / gain, 0.f), ih);
        out[o * 4 + 0] = (x1 + x2) * 0.5f / iw;
        out[o * 4 + 1] = (y1 + y2) * 0.5f / ih;
        out[o * 4 + 2] = (x2 - x1) / iw;
        out[o * 4 + 3] = (y2 - y1) / ih;
        out[4 * MAXDET + o] = cScore[k];
    }
    for (int p = t; p < nk * N_CLS; p += 256) {
        int o = p / N_CLS, c = p - o * N_CLS;
        int a = cIdx[sel[o]];
        out[5 * MAXDET + p] = pred[(long)a * 85 + 5 + c];
    }
}

extern "C" void kernel_launch(void* const* d_in, const int* in_sizes, int n_in,
                              void* d_out, int out_size, void* d_ws, size_t ws_size,
                              hipStream_t stream) {
    const float* pred = (const float*)d_in[0];
    const int* img = (const int*)d_in[1];
    const int* inp = (const int*)d_in[2];
    float* out = (float*)d_out;
    unsigned char* W = (unsigned char*)d_ws;

    unsigned* hist                = (unsigned*)(W + 0);                // 262144 B
    unsigned* meta                = (unsigned*)(W + 262144);           // 256 B
    unsigned* ord                 = (unsigned*)(W + 262400);           // 480000 B
    int* lab                      = (int*)(W + 742400);                // 480000 B
    float4* box                   = (float4*)(W + 1222400);            // 1920000 B
    unsigned long long* keys      = (unsigned long long*)(W + 3142400);// 32768 B
    unsigned* eq                  = (unsigned*)(W + 3175168);          // 16384 B
    int* cIdx                     = (int*)(W + 3191552);               // 16384 B
    float* cScore                 = (float*)(W + 3207936);             // 16384 B
    int* cLab                     = (int*)(W + 3224320);               // 16384 B
    float4* cBox                  = (float4*)(W + 3240704);            // 65536 B
    float4* oBox                  = (float4*)(W + 3306240);            // 65536 B
    float* oArea                  = (float*)(W + 3371776);             // 16384 B
    unsigned long long* M         = (unsigned long long*)(W + 3388160);// 2097152 B
    unsigned long long* keepW     = (unsigned long long*)(W + 5485312);// 512 B

    int nb = (N_ANCH + 255) / 256;
    int ndb = (N_ANCH + DBLK - 1) / DBLK;
    k_zero<<<64, 1024, 0, stream>>>(hist, meta);
    k_decode<<<ndb, DBLK, 0, stream>>>(pred, ord, lab, box, hist);
    k_select<<<1, 1024, 0, stream>>>(hist, meta, 0);
    k_hist2<<<nb, 256, 0, stream>>>(ord, meta, hist);
    k_select<<<1, 1024, 0, stream>>>(hist, meta, 1);
    k_compact<<<nb, 256, 0, stream>>>(ord, meta, keys, eq);
    k_eqsort<<<1, 1024, 0, stream>>>(eq, meta, keys);
    k_sort<<<1, 1024, 0, stream>>>(keys);
    k_gather<<<16, 256, 0, stream>>>(keys, lab, box, cIdx, cScore, cLab, cBox, meta);
    k_offbox<<<16, 256, 0, stream>>>(cLab, cBox, meta, oBox, oArea);
    k_mask<<<1024, dim3(64, 4), 0, stream>>>(oBox, oArea, M);
    k_nms<<<1, 64, 0, stream>>>(M, cScore, keepW);
    k_final<<<1, 256, 0, stream>>>(keepW, cScore, cBox, cIdx, pred, img, inp, out, out_size);
}

// Round 4
// 458.329 us; speedup vs baseline: 4.0694x; 1.6306x over previous
//
#include <hip/hip_runtime.h>
#include <math.h>

#define N_ANCH 120000
#define N_CLS  80
#define TOPK   4096
#define MAXDET 100
#define CONF   0.25f
#define IOUT   0.4f
#define DBLK   128   // anchors per decode block

// ---------- helpers ----------
__device__ __forceinline__ unsigned f2ord(float f) {
    unsigned u = __float_as_uint(f);
    return (u & 0x80000000u) ? ~u : (u | 0x80000000u);
}
__device__ __forceinline__ float ord2f(unsigned o) {
    unsigned u = (o & 0x80000000u) ? (o & 0x7FFFFFFFu) : ~o;
    return __uint_as_float(u);
}
#define ORD_NEGINF 0x007FFFFFu   // f2ord(-INFINITY)

// ---------- 0: zero hist + meta ----------
__global__ __launch_bounds__(1024) void k_zero(unsigned* hist, unsigned* meta) {
    int i = blockIdx.x * 1024 + threadIdx.x;
    if (i < 65536) hist[i] = 0u;
    if (i < 64) meta[i] = 0u;
}

// ---------- 1: decode anchors (LDS-staged, coalesced) + histogram round 1 ----------
// Invalid (score<=CONF) anchors all map to bin ORD_NEGINF>>16: wave-aggregate that
// atomic (30k same-address atomics was the round-2/3 bottleneck: 355us of serialized TCC ops).
__global__ __launch_bounds__(DBLK) void k_decode(const float* __restrict__ pred,
                                                 unsigned* __restrict__ ord,
                                                 int* __restrict__ lab,
                                                 float4* __restrict__ box,
                                                 unsigned* __restrict__ hist) {
    __shared__ float s[DBLK * 85];   // 43520 B
    int blk = blockIdx.x;
    long basef = (long)blk * (DBLK * 85);
    long remf = (long)N_ANCH * 85 - basef;
    int nf = (int)(remf < (long)(DBLK * 85) ? remf : (long)(DBLK * 85));
    int tot4 = nf >> 2;  // all block float-counts are multiples of 4
    const float4* g4 = (const float4*)(pred + basef);
    float4* s4 = (float4*)s;
    for (int i = threadIdx.x; i < tot4; i += DBLK) s4[i] = g4[i];
    __syncthreads();
    int a = blk * DBLK + threadIdx.x;
    if (a >= N_ANCH) return;
    const float* p = s + threadIdx.x * 85;  // bank = (21*lane + c) % 32 -> 2-way, free
    float x = p[0], y = p[1], w = p[2], h = p[3], obj = p[4];
    float best = p[5];
    int bl = 0;
    for (int c = 1; c < N_CLS; ++c) {
        float v = p[5 + c];
        if (v > best) { best = v; bl = c; }   // first-max (argmax) semantics
    }
    float sc = obj * best;
    float hw = w * 0.5f, hh = h * 0.5f;
    float4 b;
    b.x = x - hw; b.y = y - hh; b.z = x + hw; b.w = y + hh;
    bool valid = sc > CONF;
    float m = valid ? sc : -INFINITY;
    unsigned o = f2ord(m);
    ord[a] = o;
    lab[a] = bl;
    box[a] = b;
    unsigned long long balInv = __ballot(!valid);
    if (valid) {
        atomicAdd(&hist[o >> 16], 1u);   // ~300 distinct exponent bins: distributed, cheap
    } else {
        int lane = threadIdx.x & 63;
        if (lane == __ffsll(balInv) - 1)
            atomicAdd(&hist[ORD_NEGINF >> 16], (unsigned)__popcll(balInv));
    }
}

// ---------- 2/4: histogram select (suffix scan over 65536 bins) ----------
__global__ __launch_bounds__(1024) void k_select(unsigned* hist, unsigned* meta, int mode) {
    __shared__ unsigned part[1024];
    int t = threadIdx.x;
    unsigned target = (mode == 0) ? (unsigned)TOPK : meta[2];
    int base = t * 64;
    unsigned local = 0;
    for (int i = 0; i < 64; ++i) local += hist[base + i];
    part[t] = local;
    __syncthreads();
    for (int off = 1; off < 1024; off <<= 1) {
        unsigned v = (t + off < 1024) ? part[t + off] : 0u;
        __syncthreads();
        part[t] += v;
        __syncthreads();
    }
    unsigned incl = part[t];
    unsigned after = (t + 1 < 1024) ? part[t + 1] : 0u;
    if (after < target && incl >= target) {
        unsigned c64[64];
#pragma unroll
        for (int i = 0; i < 64; ++i) c64[i] = hist[base + i];  // independent, pipelined
        unsigned run = after;
        for (int i = 63; i >= 0; --i) {
            unsigned c = c64[i];
            if (run + c >= target) {
                if (mode == 0) {
                    meta[0] = (unsigned)(base + i);
                    meta[1] = run;
                    meta[2] = (unsigned)TOPK - run;
                } else {
                    meta[3] = (meta[0] << 16) | (unsigned)(base + i);
                    meta[4] = meta[1] + run;
                    meta[5] = meta[2] - run;
                }
                break;
            }
            run += c;
        }
    }
    if (mode == 0) {
        for (int i = 0; i < 64; ++i) hist[base + i] = 0u;
    }
}

// ---------- 3: histogram round 2 (aggregate the constant -inf pattern defensively) ----------
__global__ __launch_bounds__(256) void k_hist2(const unsigned* __restrict__ ord,
                                               const unsigned* __restrict__ meta,
                                               unsigned* __restrict__ hist) {
    int a = blockIdx.x * 256 + threadIdx.x;
    if (a >= N_ANCH) return;
    unsigned o = ord[a];
    bool inBin = ((o >> 16) == meta[0]);
    bool isInv = inBin && (o == ORD_NEGINF);
    unsigned long long balInv = __ballot(isInv);
    if (inBin) {
        if (isInv) {
            int lane = threadIdx.x & 63;
            if (lane == __ffsll(balInv) - 1)
                atomicAdd(&hist[ORD_NEGINF & 0xFFFFu], (unsigned)__popcll(balInv));
        } else {
            atomicAdd(&hist[o & 0xFFFFu], 1u);
        }
    }
}

// ---------- 5: compact (warp-aggregated counter atomics; order within sets irrelevant) ----------
__global__ __launch_bounds__(256) void k_compact(const unsigned* __restrict__ ord,
                                                 unsigned* meta,
                                                 unsigned long long* __restrict__ keys,
                                                 unsigned* __restrict__ eq) {
    int a = blockIdx.x * 256 + threadIdx.x;
    if (a >= N_ANCH) return;
    unsigned o = ord[a];
    unsigned T = meta[3];
    int lane = threadIdx.x & 63;
    bool isGt = (o > T);
    bool isEq = (o == T);
    unsigned long long balGt = __ballot(isGt);
    unsigned long long balEq = __ballot(isEq);
    if (isGt) {
        int leader = __ffsll(balGt) - 1;
        unsigned base = 0;
        if (lane == leader) base = atomicAdd(&meta[6], (unsigned)__popcll(balGt));
        base = (unsigned)__shfl((int)base, leader);
        unsigned p = base + (unsigned)__popcll(balGt & ((1ull << lane) - 1ull));
        keys[p] = ((unsigned long long)o << 32) | (unsigned)(~(unsigned)a);
    } else if (isEq) {
        int leader = __ffsll(balEq) - 1;
        unsigned base = 0;
        if (lane == leader) base = atomicAdd(&meta[7], (unsigned)__popcll(balEq));
        base = (unsigned)__shfl((int)base, leader);
        unsigned p = base + (unsigned)__popcll(balEq & ((1ull << lane) - 1ull));
        if (p < TOPK) eq[p] = (unsigned)a;
    }
}

// ---------- 6: tie handling. Membership = remEq smallest tie indices. ----------
__global__ __launch_bounds__(1024) void k_eqsort(const unsigned* __restrict__ eq,
                                                 unsigned* meta,
                                                 unsigned long long* keys) {
    __shared__ unsigned s[TOPK];
    int t = threadIdx.x;
    unsigned n = meta[7]; if (n > TOPK) n = TOPK;
    unsigned remEq = meta[5];
    unsigned baseA = meta[4];
    unsigned T = meta[3];
    if (remEq == 0) return;
    if (n > remEq) {
        unsigned m = 1; while (m < n) m <<= 1;
        for (unsigned i = t; i < m; i += 1024) s[i] = (i < n) ? eq[i] : 0xFFFFFFFFu;
        __syncthreads();
        for (unsigned k = 2; k <= m; k <<= 1)
            for (unsigned j = k >> 1; j > 0; j >>= 1) {
                for (unsigned idx = t; idx < m; idx += 1024) {
                    unsigned ixj = idx ^ j;
                    if (ixj > idx) {
                        unsigned a = s[idx], b = s[ixj];
                        bool asc = ((idx & k) == 0);
                        bool sw = asc ? (a > b) : (a < b);
                        if (sw) { s[idx] = b; s[ixj] = a; }
                    }
                }
                __syncthreads();
            }
        for (unsigned r = t; r < remEq; r += 1024)
            keys[baseA + r] = ((unsigned long long)T << 32) | (unsigned)(~s[r]);
    } else {
        for (unsigned r = t; r < remEq; r += 1024)
            keys[baseA + r] = ((unsigned long long)T << 32) | (unsigned)(~eq[r]);
    }
}

// ---------- 7: bitonic sort 4096 keys descending ----------
__global__ __launch_bounds__(1024) void k_sort(unsigned long long* keys) {
    __shared__ unsigned long long s[TOPK];
    int t = threadIdx.x;
    for (int i = t; i < TOPK; i += 1024) s[i] = keys[i];
    __syncthreads();
    for (int k = 2; k <= TOPK; k <<= 1)
        for (int j = k >> 1; j > 0; j >>= 1) {
            for (int idx = t; idx < TOPK; idx += 1024) {
                int ixj = idx ^ j;
                if (ixj > idx) {
                    unsigned long long a = s[idx], b = s[ixj];
                    bool desc = ((idx & k) == 0);
                    bool sw = desc ? (a < b) : (a > b);
                    if (sw) { s[idx] = b; s[ixj] = a; }
                }
            }
            __syncthreads();
        }
    for (int i = t; i < TOPK; i += 1024) keys[i] = s[i];
}

// ---------- 8: gather + max_coord ----------
__global__ __launch_bounds__(256) void k_gather(const unsigned long long* __restrict__ keys,
                                                const int* __restrict__ lab,
                                                const float4* __restrict__ box,
                                                int* __restrict__ cIdx,
                                                float* __restrict__ cScore,
                                                int* __restrict__ cLab,
                                                float4* __restrict__ cBox,
                                                unsigned* meta) {
    int k = blockIdx.x * 256 + threadIdx.x;
    unsigned long long key = keys[k];
    unsigned o = (unsigned)(key >> 32);
    unsigned a = ~(unsigned)(key & 0xFFFFFFFFu);
    float sc = ord2f(o);
    cIdx[k] = (int)a;
    cScore[k] = sc;
    cLab[k] = lab[a];
    float4 b = box[a];
    cBox[k] = b;
    if (sc > CONF) {
        if (b.x > 0.f) atomicMax(&meta[8], __float_as_uint(b.x));
        if (b.y > 0.f) atomicMax(&meta[8], __float_as_uint(b.y));
        if (b.z > 0.f) atomicMax(&meta[8], __float_as_uint(b.z));
        if (b.w > 0.f) atomicMax(&meta[8], __float_as_uint(b.w));
    }
}

// ---------- 9: offset boxes + areas ----------
__global__ __launch_bounds__(256) void k_offbox(const int* __restrict__ cLab,
                                                const float4* __restrict__ cBox,
                                                const unsigned* __restrict__ meta,
                                                float4* __restrict__ oBox,
                                                float* __restrict__ oArea) {
    int k = blockIdx.x * 256 + threadIdx.x;
    float mc = __uint_as_float(meta[8]) + 1.0f;
    float off = (float)cLab[k] * mc;
    float4 b = cBox[k];
    float4 ob;
    ob.x = b.x + off; ob.y = b.y + off; ob.z = b.z + off; ob.w = b.w + off;
    oBox[k] = ob;
    oArea[k] = fmaxf(ob.z - ob.x, 0.f) * fmaxf(ob.w - ob.y, 0.f);
}

// ---------- 10: suppression bitmask ----------
__global__ __launch_bounds__(256) void k_mask(const float4* __restrict__ oBox,
                                              const float* __restrict__ oArea,
                                              unsigned long long* __restrict__ M) {
    int w = threadIdx.x;
    int i = blockIdx.x * 4 + threadIdx.y;
    float4 bi = oBox[i];
    float ai = oArea[i];
    unsigned long long bits = 0ull;
    int j0 = w << 6;
    for (int b = 0; b < 64; ++b) {
        int j = j0 + b;
        float4 bj = oBox[j];
        float aj = oArea[j];
        float ix1 = fmaxf(bi.x, bj.x), iy1 = fmaxf(bi.y, bj.y);
        float ix2 = fminf(bi.z, bj.z), iy2 = fminf(bi.w, bj.w);
        float inter = fmaxf(ix2 - ix1, 0.f) * fmaxf(iy2 - iy1, 0.f);
        float uni = ai + aj - inter;
        float iou = inter / fmaxf(uni, 1e-9f);
        if ((j > i) & (iou > IOUT)) bits |= (1ull << b);
    }
    M[(long)i * 64 + w] = bits;
}

// ---------- 11: greedy NMS, single wave, 64x64 tiled ----------
__global__ __launch_bounds__(64) void k_nms(const unsigned long long* __restrict__ M,
                                            const float* __restrict__ cScore,
                                            unsigned long long* __restrict__ keepW) {
    int lane = threadIdx.x;
    unsigned long long S = 0ull;
    int base0 = lane << 6;
#pragma unroll 8
    for (int b = 0; b < 64; ++b) {
        float sc = cScore[base0 + b];
        if (!(sc > CONF)) S |= (1ull << b);
    }
    unsigned long long d = M[(long)lane * 64 + 0];
    for (int t = 0; t < 64; ++t) {
        unsigned long long dcur = d;
        if (t + 1 < 64) d = M[(long)((t + 1) * 64 + lane) * 64 + (t + 1)];
        unsigned s_lo = (unsigned)__builtin_amdgcn_readlane((int)(unsigned)S, t);
        unsigned s_hi = (unsigned)__builtin_amdgcn_readlane((int)(unsigned)(S >> 32), t);
        unsigned long long s_tile = ((unsigned long long)s_hi << 32) | s_lo;
#pragma unroll
        for (int b = 0; b < 64; ++b) {
            unsigned rl = (unsigned)__builtin_amdgcn_readlane((int)(unsigned)dcur, b);
            unsigned rh = (unsigned)__builtin_amdgcn_readlane((int)(unsigned)(dcur >> 32), b);
            unsigned long long row = ((unsigned long long)rh << 32) | rl;
            unsigned long long mask = 0ull - (((~s_tile) >> b) & 1ull);
            s_tile |= row & mask;
        }
        unsigned long long kt = ~s_tile;
        const unsigned long long* Mrow = M + (long)(t << 6) * 64 + lane;
#pragma unroll 16
        for (int b = 0; b < 64; ++b) {
            unsigned long long row = Mrow[(long)b * 64];
            unsigned long long mask = 0ull - ((kt >> b) & 1ull);
            S |= row & mask;
        }
    }
    keepW[lane] = ~S;
}

// ---------- 12: finalize ----------
__global__ __launch_bounds__(256) void k_final(const unsigned long long* __restrict__ keepW,
                                               const float* __restrict__ cScore,
                                               const float4* __restrict__ cBox,
                                               const int* __restrict__ cIdx,
                                               const float* __restrict__ pred,
                                               const int* __restrict__ img,
                                               const int* __restrict__ inp,
                                               float* __restrict__ out,
                                               int out_size) {
    __shared__ int sel[MAXDET];
    __shared__ int nsel;
    int t = threadIdx.x;
    for (int i = t; i < out_size; i += 256) out[i] = 0.f;
    if (t == 0) nsel = 0;
    __syncthreads();
    if (t < 64) {
        unsigned long long kw = keepW[t];
        int cnt = __popcll(kw);
        int incl = cnt;
        for (int off = 1; off < 64; off <<= 1) {
            int v = __shfl_up(incl, off);
            if (t >= off) incl += v;
        }
        int rk = incl - cnt;
        if (t == 63) nsel = (incl < MAXDET) ? incl : MAXDET;
        unsigned long long m = kw;
        while (m) {
            int b = __ffsll((unsigned long long)m) - 1;
            m &= m - 1;
            if (rk < MAXDET) sel[rk] = (t << 6) + b;
            ++rk;
        }
    }
    __syncthreads();
    int nk = nsel;
    int ih_i = img[0], iw_i = img[1];
    int nh_i = inp[0], nw_i = inp[1];
    if (iw_i == 0) iw_i = img[2];
    if (nw_i == 0) nw_i = inp[2];
    float ih = (float)ih_i, iw = (float)iw_i;
    float nh = (float)nh_i, nw = (float)nw_i;
    float gain = fminf(nh / ih, nw / iw);
    float pad0 = (nh - ih * gain) * 0.5f;
    float pad1 = (nw - iw * gain) * 0.5f;
    for (int o = t; o < nk; o += 256) {
        int k = sel[o];
        float4 b = cBox[k];
        float x1 = fminf(fmaxf((b.x - pad1) / gain, 0.f), iw);
        float y1 = fminf(fmaxf((b.y - pad0) / gain, 0.f), ih);
        float x2 = fminf(fmaxf((b.z - pad1) / gain, 0.f), iw);
        float y2 = fminf(fmaxf((b.w - pad0) / gain, 0.f), ih);
        out[o * 4 + 0] = (x1 + x2) * 0.5f / iw;
        out[o * 4 + 1] = (y1 + y2) * 0.5f / ih;
        out[o * 4 + 2] = (x2 - x1) / iw;
        out[o * 4 + 3] = (y2 - y1) / ih;
        out[4 * MAXDET + o] = cScore[k];
    }
    for (int p = t; p < nk * N_CLS; p += 256) {
        int o = p / N_CLS, c = p - o * N_CLS;
        int a = cIdx[sel[o]];
        out[5 * MAXDET + p] = pred[(long)a * 85 + 5 + c];
    }
}

extern "C" void kernel_launch(void* const* d_in, const int* in_sizes, int n_in,
                              void* d_out, int out_size, void* d_ws, size_t ws_size,
                              hipStream_t stream) {
    const float* pred = (const float*)d_in[0];
    const int* img = (const int*)d_in[1];
    const int* inp = (const int*)d_in[2];
    float* out = (float*)d_out;
    unsigned char* W = (unsigned char*)d_ws;

    unsigned* hist                = (unsigned*)(W + 0);                // 262144 B
    unsigned* meta                = (unsigned*)(W + 262144);           // 256 B
    unsigned* ord                 = (unsigned*)(W + 262400);           // 480000 B
    int* lab                      = (int*)(W + 742400);                // 480000 B
    float4* box                   = (float4*)(W + 1222400);            // 1920000 B
    unsigned long long* keys      = (unsigned long long*)(W + 3142400);// 32768 B
    unsigned* eq                  = (unsigned*)(W + 3175168);          // 16384 B
    int* cIdx                     = (int*)(W + 3191552);               // 16384 B
    float* cScore                 = (float*)(W + 3207936);             // 16384 B
    int* cLab                     = (int*)(W + 3224320);               // 16384 B
    float4* cBox                  = (float4*)(W + 3240704);            // 65536 B
    float4* oBox                  = (float4*)(W + 3306240);            // 65536 B
    float* oArea                  = (float*)(W + 3371776);             // 16384 B
    unsigned long long* M         = (unsigned long long*)(W + 3388160);// 2097152 B
    unsigned long long* keepW     = (unsigned long long*)(W + 5485312);// 512 B

    int nb = (N_ANCH + 255) / 256;
    int ndb = (N_ANCH + DBLK - 1) / DBLK;
    k_zero<<<64, 1024, 0, stream>>>(hist, meta);
    k_decode<<<ndb, DBLK, 0, stream>>>(pred, ord, lab, box, hist);
    k_select<<<1, 1024, 0, stream>>>(hist, meta, 0);
    k_hist2<<<nb, 256, 0, stream>>>(ord, meta, hist);
    k_select<<<1, 1024, 0, stream>>>(hist, meta, 1);
    k_compact<<<nb, 256, 0, stream>>>(ord, meta, keys, eq);
    k_eqsort<<<1, 1024, 0, stream>>>(eq, meta, keys);
    k_sort<<<1, 1024, 0, stream>>>(keys);
    k_gather<<<16, 256, 0, stream>>>(keys, lab, box, cIdx, cScore, cLab, cBox, meta);
    k_offbox<<<16, 256, 0, stream>>>(cLab, cBox, meta, oBox, oArea);
    k_mask<<<1024, dim3(64, 4), 0, stream>>>(oBox, oArea, M);
    k_nms<<<1, 64, 0, stream>>>(M, cScore, keepW);
    k_final<<<1, 256, 0, stream>>>(keepW, cScore, cBox, cIdx, pred, img, inp, out, out_size);
}

// Round 5
// 436.796 us; speedup vs baseline: 4.2700x; 1.0493x over previous
//
#include <hip/hip_runtime.h>
#include <math.h>

#define N_ANCH 120000
#define N_CLS  80
#define TOPK   4096
#define MAXDET 100
#define CONF   0.25f
#define IOUT   0.4f
#define DBLK   128   // anchors per decode block

// ---------- helpers ----------
__device__ __forceinline__ unsigned f2ord(float f) {
    unsigned u = __float_as_uint(f);
    return (u & 0x80000000u) ? ~u : (u | 0x80000000u);
}
__device__ __forceinline__ float ord2f(unsigned o) {
    unsigned u = (o & 0x80000000u) ? (o & 0x7FFFFFFFu) : ~o;
    return __uint_as_float(u);
}
#define ORD_NEGINF 0x007FFFFFu   // f2ord(-INFINITY)

// ---------- 0: zero hist + meta ----------
__global__ __launch_bounds__(1024) void k_zero(unsigned* hist, unsigned* meta) {
    int i = blockIdx.x * 1024 + threadIdx.x;
    if (i < 65536) hist[i] = 0u;
    if (i < 64) meta[i] = 0u;
}

// ---------- 1: decode anchors (LDS-staged, coalesced) + histogram round 1 ----------
__global__ __launch_bounds__(DBLK) void k_decode(const float* __restrict__ pred,
                                                 unsigned* __restrict__ ord,
                                                 int* __restrict__ lab,
                                                 float4* __restrict__ box,
                                                 unsigned* __restrict__ hist) {
    __shared__ float s[DBLK * 85];   // 43520 B
    int blk = blockIdx.x;
    long basef = (long)blk * (DBLK * 85);
    long remf = (long)N_ANCH * 85 - basef;
    int nf = (int)(remf < (long)(DBLK * 85) ? remf : (long)(DBLK * 85));
    int tot4 = nf >> 2;  // all block float-counts are multiples of 4
    const float4* g4 = (const float4*)(pred + basef);
    float4* s4 = (float4*)s;
    for (int i = threadIdx.x; i < tot4; i += DBLK) s4[i] = g4[i];
    __syncthreads();
    int a = blk * DBLK + threadIdx.x;
    if (a >= N_ANCH) return;
    const float* p = s + threadIdx.x * 85;  // bank = (21*lane + c) % 32 -> 2-way, free
    float x = p[0], y = p[1], w = p[2], h = p[3], obj = p[4];
    float best = p[5];
    int bl = 0;
    for (int c = 1; c < N_CLS; ++c) {
        float v = p[5 + c];
        if (v > best) { best = v; bl = c; }   // first-max (argmax) semantics
    }
    float sc = obj * best;
    float hw = w * 0.5f, hh = h * 0.5f;
    float4 b;
    b.x = x - hw; b.y = y - hh; b.z = x + hw; b.w = y + hh;
    bool valid = sc > CONF;
    float m = valid ? sc : -INFINITY;
    unsigned o = f2ord(m);
    ord[a] = o;
    lab[a] = bl;
    box[a] = b;
    unsigned long long balInv = __ballot(!valid);
    if (valid) {
        atomicAdd(&hist[o >> 16], 1u);   // ~300 distinct exponent bins: distributed, cheap
    } else {
        int lane = threadIdx.x & 63;
        if (lane == __ffsll(balInv) - 1)
            atomicAdd(&hist[ORD_NEGINF >> 16], (unsigned)__popcll(balInv));
    }
}

// ---------- 2/4: histogram select (suffix scan over 65536 bins) ----------
__global__ __launch_bounds__(1024) void k_select(unsigned* hist, unsigned* meta, int mode) {
    __shared__ unsigned part[1024];
    int t = threadIdx.x;
    unsigned target = (mode == 0) ? (unsigned)TOPK : meta[2];
    int base = t * 64;
    unsigned local = 0;
    for (int i = 0; i < 64; ++i) local += hist[base + i];
    part[t] = local;
    __syncthreads();
    for (int off = 1; off < 1024; off <<= 1) {
        unsigned v = (t + off < 1024) ? part[t + off] : 0u;
        __syncthreads();
        part[t] += v;
        __syncthreads();
    }
    unsigned incl = part[t];
    unsigned after = (t + 1 < 1024) ? part[t + 1] : 0u;
    if (after < target && incl >= target) {
        unsigned c64[64];
#pragma unroll
        for (int i = 0; i < 64; ++i) c64[i] = hist[base + i];  // independent, pipelined
        unsigned run = after;
        for (int i = 63; i >= 0; --i) {
            unsigned c = c64[i];
            if (run + c >= target) {
                if (mode == 0) {
                    meta[0] = (unsigned)(base + i);
                    meta[1] = run;
                    meta[2] = (unsigned)TOPK - run;
                } else {
                    meta[3] = (meta[0] << 16) | (unsigned)(base + i);
                    meta[4] = meta[1] + run;
                    meta[5] = meta[2] - run;
                }
                break;
            }
            run += c;
        }
    }
    if (mode == 0) {
        for (int i = 0; i < 64; ++i) hist[base + i] = 0u;
    }
}

// ---------- 3: histogram round 2 (aggregate the constant -inf pattern defensively) ----------
__global__ __launch_bounds__(256) void k_hist2(const unsigned* __restrict__ ord,
                                               const unsigned* __restrict__ meta,
                                               unsigned* __restrict__ hist) {
    int a = blockIdx.x * 256 + threadIdx.x;
    if (a >= N_ANCH) return;
    unsigned o = ord[a];
    bool inBin = ((o >> 16) == meta[0]);
    bool isInv = inBin && (o == ORD_NEGINF);
    unsigned long long balInv = __ballot(isInv);
    if (inBin) {
        if (isInv) {
            int lane = threadIdx.x & 63;
            if (lane == __ffsll(balInv) - 1)
                atomicAdd(&hist[ORD_NEGINF & 0xFFFFu], (unsigned)__popcll(balInv));
        } else {
            atomicAdd(&hist[o & 0xFFFFu], 1u);
        }
    }
}

// ---------- 5: compact (warp-aggregated counter atomics; order within sets irrelevant) ----------
__global__ __launch_bounds__(256) void k_compact(const unsigned* __restrict__ ord,
                                                 unsigned* meta,
                                                 unsigned long long* __restrict__ keys,
                                                 unsigned* __restrict__ eq) {
    int a = blockIdx.x * 256 + threadIdx.x;
    if (a >= N_ANCH) return;
    unsigned o = ord[a];
    unsigned T = meta[3];
    int lane = threadIdx.x & 63;
    bool isGt = (o > T);
    bool isEq = (o == T);
    unsigned long long balGt = __ballot(isGt);
    unsigned long long balEq = __ballot(isEq);
    if (isGt) {
        int leader = __ffsll(balGt) - 1;
        unsigned base = 0;
        if (lane == leader) base = atomicAdd(&meta[6], (unsigned)__popcll(balGt));
        base = (unsigned)__shfl((int)base, leader);
        unsigned p = base + (unsigned)__popcll(balGt & ((1ull << lane) - 1ull));
        keys[p] = ((unsigned long long)o << 32) | (unsigned)(~(unsigned)a);
    } else if (isEq) {
        int leader = __ffsll(balEq) - 1;
        unsigned base = 0;
        if (lane == leader) base = atomicAdd(&meta[7], (unsigned)__popcll(balEq));
        base = (unsigned)__shfl((int)base, leader);
        unsigned p = base + (unsigned)__popcll(balEq & ((1ull << lane) - 1ull));
        if (p < TOPK) eq[p] = (unsigned)a;
    }
}

// ---------- 6: tie handling. Membership = remEq smallest tie indices. ----------
__global__ __launch_bounds__(1024) void k_eqsort(const unsigned* __restrict__ eq,
                                                 unsigned* meta,
                                                 unsigned long long* keys) {
    __shared__ unsigned s[TOPK];
    int t = threadIdx.x;
    unsigned n = meta[7]; if (n > TOPK) n = TOPK;
    unsigned remEq = meta[5];
    unsigned baseA = meta[4];
    unsigned T = meta[3];
    if (remEq == 0) return;
    if (n > remEq) {
        unsigned m = 1; while (m < n) m <<= 1;
        for (unsigned i = t; i < m; i += 1024) s[i] = (i < n) ? eq[i] : 0xFFFFFFFFu;
        __syncthreads();
        for (unsigned k = 2; k <= m; k <<= 1)
            for (unsigned j = k >> 1; j > 0; j >>= 1) {
                for (unsigned idx = t; idx < m; idx += 1024) {
                    unsigned ixj = idx ^ j;
                    if (ixj > idx) {
                        unsigned a = s[idx], b = s[ixj];
                        bool asc = ((idx & k) == 0);
                        bool sw = asc ? (a > b) : (a < b);
                        if (sw) { s[idx] = b; s[ixj] = a; }
                    }
                }
                __syncthreads();
            }
        for (unsigned r = t; r < remEq; r += 1024)
            keys[baseA + r] = ((unsigned long long)T << 32) | (unsigned)(~s[r]);
    } else {
        for (unsigned r = t; r < remEq; r += 1024)
            keys[baseA + r] = ((unsigned long long)T << 32) | (unsigned)(~eq[r]);
    }
}

// ---------- 7: bitonic sort 4096 keys descending ----------
__global__ __launch_bounds__(1024) void k_sort(unsigned long long* keys) {
    __shared__ unsigned long long s[TOPK];
    int t = threadIdx.x;
    for (int i = t; i < TOPK; i += 1024) s[i] = keys[i];
    __syncthreads();
    for (int k = 2; k <= TOPK; k <<= 1)
        for (int j = k >> 1; j > 0; j >>= 1) {
            for (int idx = t; idx < TOPK; idx += 1024) {
                int ixj = idx ^ j;
                if (ixj > idx) {
                    unsigned long long a = s[idx], b = s[ixj];
                    bool desc = ((idx & k) == 0);
                    bool sw = desc ? (a < b) : (a > b);
                    if (sw) { s[idx] = b; s[ixj] = a; }
                }
            }
            __syncthreads();
        }
    for (int i = t; i < TOPK; i += 1024) keys[i] = s[i];
}

// ---------- 8: gather + max_coord ----------
__global__ __launch_bounds__(256) void k_gather(const unsigned long long* __restrict__ keys,
                                                const int* __restrict__ lab,
                                                const float4* __restrict__ box,
                                                int* __restrict__ cIdx,
                                                float* __restrict__ cScore,
                                                int* __restrict__ cLab,
                                                float4* __restrict__ cBox,
                                                unsigned* meta) {
    int k = blockIdx.x * 256 + threadIdx.x;
    unsigned long long key = keys[k];
    unsigned o = (unsigned)(key >> 32);
    unsigned a = ~(unsigned)(key & 0xFFFFFFFFu);
    float sc = ord2f(o);
    cIdx[k] = (int)a;
    cScore[k] = sc;
    cLab[k] = lab[a];
    float4 b = box[a];
    cBox[k] = b;
    if (sc > CONF) {
        if (b.x > 0.f) atomicMax(&meta[8], __float_as_uint(b.x));
        if (b.y > 0.f) atomicMax(&meta[8], __float_as_uint(b.y));
        if (b.z > 0.f) atomicMax(&meta[8], __float_as_uint(b.z));
        if (b.w > 0.f) atomicMax(&meta[8], __float_as_uint(b.w));
    }
}

// ---------- 9: offset boxes + areas ----------
__global__ __launch_bounds__(256) void k_offbox(const int* __restrict__ cLab,
                                                const float4* __restrict__ cBox,
                                                const unsigned* __restrict__ meta,
                                                float4* __restrict__ oBox,
                                                float* __restrict__ oArea) {
    int k = blockIdx.x * 256 + threadIdx.x;
    float mc = __uint_as_float(meta[8]) + 1.0f;
    float off = (float)cLab[k] * mc;
    float4 b = cBox[k];
    float4 ob;
    ob.x = b.x + off; ob.y = b.y + off; ob.z = b.z + off; ob.w = b.w + off;
    oBox[k] = ob;
    oArea[k] = fmaxf(ob.z - ob.x, 0.f) * fmaxf(ob.w - ob.y, 0.f);
}

// ---------- 10: suppression bitmask ----------
__global__ __launch_bounds__(256) void k_mask(const float4* __restrict__ oBox,
                                              const float* __restrict__ oArea,
                                              unsigned long long* __restrict__ M) {
    int w = threadIdx.x;
    int i = blockIdx.x * 4 + threadIdx.y;
    float4 bi = oBox[i];
    float ai = oArea[i];
    unsigned long long bits = 0ull;
    int j0 = w << 6;
    for (int b = 0; b < 64; ++b) {
        int j = j0 + b;
        float4 bj = oBox[j];
        float aj = oArea[j];
        float ix1 = fmaxf(bi.x, bj.x), iy1 = fmaxf(bi.y, bj.y);
        float ix2 = fminf(bi.z, bj.z), iy2 = fminf(bi.w, bj.w);
        float inter = fmaxf(ix2 - ix1, 0.f) * fmaxf(iy2 - iy1, 0.f);
        float uni = ai + aj - inter;
        float iou = inter / fmaxf(uni, 1e-9f);
        if ((j > i) & (iou > IOUT)) bits |= (1ull << b);
    }
    M[(long)i * 64 + w] = bits;
}

// ---------- 11: greedy NMS, single wave, 64x64 tiled, register double-buffered ----------
// Lane w owns suppression word w (columns 64w..64w+63) in register S.
// Tile t's full 32KB block lives in 64 u64 registers/lane (RA or RB); while
// processing tile t, all 64 loads of tile t+1 are in flight -> latency hidden.
// Diagonal word of row b in tile t = readlane(R[b], t) (no separate diag load).
__global__ __launch_bounds__(64) void k_nms(const unsigned long long* __restrict__ M,
                                            const float* __restrict__ cScore,
                                            unsigned long long* __restrict__ keepW) {
    int lane = threadIdx.x;
    unsigned long long S = 0ull;
    // invalid-score bits: word b = ballot of lanes reading cScore[b*64+lane] (coalesced)
#pragma unroll 8
    for (int b = 0; b < 64; ++b) {
        float sc = cScore[(b << 6) + lane];
        unsigned long long bal = __ballot(!(sc > CONF));
        if (lane == b) S = bal;
    }
    const unsigned long long* Ml = M + lane;
    unsigned long long RA[64], RB[64];
#pragma unroll
    for (int b = 0; b < 64; ++b) RA[b] = Ml[(long)b * 64];

#define NMS_TILE(R, t)                                                                              \
    {                                                                                               \
        unsigned s_lo = (unsigned)__builtin_amdgcn_readlane((int)(unsigned)S, (t));                 \
        unsigned s_hi = (unsigned)__builtin_amdgcn_readlane((int)(unsigned)(S >> 32), (t));         \
        unsigned long long s_tile = ((unsigned long long)s_hi << 32) | s_lo;                        \
        _Pragma("unroll")                                                                           \
        for (int b = 0; b < 64; ++b) {                                                              \
            unsigned rl = (unsigned)__builtin_amdgcn_readlane((int)(unsigned)R[b], (t));            \
            unsigned rh = (unsigned)__builtin_amdgcn_readlane((int)(unsigned)(R[b] >> 32), (t));    \
            unsigned long long row = ((unsigned long long)rh << 32) | rl;                           \
            unsigned long long mask = 0ull - (((~s_tile) >> b) & 1ull);                             \
            s_tile |= row & mask;                                                                   \
        }                                                                                           \
        unsigned long long kt = ~s_tile;                                                            \
        unsigned long long a0 = 0, a1 = 0, a2 = 0, a3 = 0, a4 = 0, a5 = 0, a6 = 0, a7 = 0;          \
        _Pragma("unroll")                                                                           \
        for (int b = 0; b < 64; b += 8) {                                                           \
            a0 |= R[b + 0] & (0ull - ((kt >> (b + 0)) & 1ull));                                     \
            a1 |= R[b + 1] & (0ull - ((kt >> (b + 1)) & 1ull));                                     \
            a2 |= R[b + 2] & (0ull - ((kt >> (b + 2)) & 1ull));                                     \
            a3 |= R[b + 3] & (0ull - ((kt >> (b + 3)) & 1ull));                                     \
            a4 |= R[b + 4] & (0ull - ((kt >> (b + 4)) & 1ull));                                     \
            a5 |= R[b + 5] & (0ull - ((kt >> (b + 5)) & 1ull));                                     \
            a6 |= R[b + 6] & (0ull - ((kt >> (b + 6)) & 1ull));                                     \
            a7 |= R[b + 7] & (0ull - ((kt >> (b + 7)) & 1ull));                                     \
        }                                                                                           \
        S |= ((a0 | a1) | (a2 | a3)) | ((a4 | a5) | (a6 | a7));                                     \
    }

    for (int t = 0; t < 64; t += 2) {
        // prefetch tile t+1 (always exists: t max = 62)
#pragma unroll
        for (int b = 0; b < 64; ++b) RB[b] = Ml[(long)((t + 1) * 64 + b) * 64];
        NMS_TILE(RA, t);
        if (t + 2 < 64) {
#pragma unroll
            for (int b = 0; b < 64; ++b) RA[b] = Ml[(long)((t + 2) * 64 + b) * 64];
        }
        NMS_TILE(RB, t + 1);
    }
#undef NMS_TILE
    keepW[lane] = ~S;
}

// ---------- 12: finalize ----------
__global__ __launch_bounds__(256) void k_final(const unsigned long long* __restrict__ keepW,
                                               const float* __restrict__ cScore,
                                               const float4* __restrict__ cBox,
                                               const int* __restrict__ cIdx,
                                               const float* __restrict__ pred,
                                               const int* __restrict__ img,
                                               const int* __restrict__ inp,
                                               float* __restrict__ out,
                                               int out_size) {
    __shared__ int sel[MAXDET];
    __shared__ int nsel;
    int t = threadIdx.x;
    for (int i = t; i < out_size; i += 256) out[i] = 0.f;
    if (t == 0) nsel = 0;
    __syncthreads();
    if (t < 64) {
        unsigned long long kw = keepW[t];
        int cnt = __popcll(kw);
        int incl = cnt;
        for (int off = 1; off < 64; off <<= 1) {
            int v = __shfl_up(incl, off);
            if (t >= off) incl += v;
        }
        int rk = incl - cnt;
        if (t == 63) nsel = (incl < MAXDET) ? incl : MAXDET;
        unsigned long long m = kw;
        while (m) {
            int b = __ffsll((unsigned long long)m) - 1;
            m &= m - 1;
            if (rk < MAXDET) sel[rk] = (t << 6) + b;
            ++rk;
        }
    }
    __syncthreads();
    int nk = nsel;
    int ih_i = img[0], iw_i = img[1];
    int nh_i = inp[0], nw_i = inp[1];
    if (iw_i == 0) iw_i = img[2];
    if (nw_i == 0) nw_i = inp[2];
    float ih = (float)ih_i, iw = (float)iw_i;
    float nh = (float)nh_i, nw = (float)nw_i;
    float gain = fminf(nh / ih, nw / iw);
    float pad0 = (nh - ih * gain) * 0.5f;
    float pad1 = (nw - iw * gain) * 0.5f;
    for (int o = t; o < nk; o += 256) {
        int k = sel[o];
        float4 b = cBox[k];
        float x1 = fminf(fmaxf((b.x - pad1) / gain, 0.f), iw);
        float y1 = fminf(fmaxf((b.y - pad0) / gain, 0.f), ih);
        float x2 = fminf(fmaxf((b.z - pad1) / gain, 0.f), iw);
        float y2 = fminf(fmaxf((b.w - pad0) / gain, 0.f), ih);
        out[o * 4 + 0] = (x1 + x2) * 0.5f / iw;
        out[o * 4 + 1] = (y1 + y2) * 0.5f / ih;
        out[o * 4 + 2] = (x2 - x1) / iw;
        out[o * 4 + 3] = (y2 - y1) / ih;
        out[4 * MAXDET + o] = cScore[k];
    }
    for (int p = t; p < nk * N_CLS; p += 256) {
        int o = p / N_CLS, c = p - o * N_CLS;
        int a = cIdx[sel[o]];
        out[5 * MAXDET + p] = pred[(long)a * 85 + 5 + c];
    }
}

extern "C" void kernel_launch(void* const* d_in, const int* in_sizes, int n_in,
                              void* d_out, int out_size, void* d_ws, size_t ws_size,
                              hipStream_t stream) {
    const float* pred = (const float*)d_in[0];
    const int* img = (const int*)d_in[1];
    const int* inp = (const int*)d_in[2];
    float* out = (float*)d_out;
    unsigned char* W = (unsigned char*)d_ws;

    unsigned* hist                = (unsigned*)(W + 0);                // 262144 B
    unsigned* meta                = (unsigned*)(W + 262144);           // 256 B
    unsigned* ord                 = (unsigned*)(W + 262400);           // 480000 B
    int* lab                      = (int*)(W + 742400);                // 480000 B
    float4* box                   = (float4*)(W + 1222400);            // 1920000 B
    unsigned long long* keys      = (unsigned long long*)(W + 3142400);// 32768 B
    unsigned* eq                  = (unsigned*)(W + 3175168);          // 16384 B
    int* cIdx                     = (int*)(W + 3191552);               // 16384 B
    float* cScore                 = (float*)(W + 3207936);             // 16384 B
    int* cLab                     = (int*)(W + 3224320);               // 16384 B
    float4* cBox                  = (float4*)(W + 3240704);            // 65536 B
    float4* oBox                  = (float4*)(W + 3306240);            // 65536 B
    float* oArea                  = (float*)(W + 3371776);             // 16384 B
    unsigned long long* M         = (unsigned long long*)(W + 3388160);// 2097152 B
    unsigned long long* keepW     = (unsigned long long*)(W + 5485312);// 512 B

    int nb = (N_ANCH + 255) / 256;
    int ndb = (N_ANCH + DBLK - 1) / DBLK;
    k_zero<<<64, 1024, 0, stream>>>(hist, meta);
    k_decode<<<ndb, DBLK, 0, stream>>>(pred, ord, lab, box, hist);
    k_select<<<1, 1024, 0, stream>>>(hist, meta, 0);
    k_hist2<<<nb, 256, 0, stream>>>(ord, meta, hist);
    k_select<<<1, 1024, 0, stream>>>(hist, meta, 1);
    k_compact<<<nb, 256, 0, stream>>>(ord, meta, keys, eq);
    k_eqsort<<<1, 1024, 0, stream>>>(eq, meta, keys);
    k_sort<<<1, 1024, 0, stream>>>(keys);
    k_gather<<<16, 256, 0, stream>>>(keys, lab, box, cIdx, cScore, cLab, cBox, meta);
    k_offbox<<<16, 256, 0, stream>>>(cLab, cBox, meta, oBox, oArea);
    k_mask<<<1024, dim3(64, 4), 0, stream>>>(oBox, oArea, M);
    k_nms<<<1, 64, 0, stream>>>(M, cScore, keepW);
    k_final<<<1, 256, 0, stream>>>(keepW, cScore, cBox, cIdx, pred, img, inp, out, out_size);
}